// Round 4
// baseline (2879.426 us; speedup 1.0000x reference)
//
#include <hip/hip_runtime.h>

#define NN    100000
#define IND   512
#define HID   128
#define OUTD  64
#define NBUCK 782          // ceil(NN/128); bucket = dst >> 7
#define NB    128          // partition blocks

typedef _Float16 half8_t __attribute__((ext_vector_type(8)));
typedef _Float16 half4_t __attribute__((ext_vector_type(4)));
typedef float f32x4 __attribute__((ext_vector_type(4)));

// ---------------- prep: W1t[c][k] = (f16)W1[k][c], W2t[c][k] = (f16)W2[k][c] ----------------
__global__ __launch_bounds__(256) void prep_k(const float* __restrict__ W1,
                                              const float* __restrict__ W2,
                                              _Float16* __restrict__ W1t,
                                              _Float16* __restrict__ W2t) {
    int idx = blockIdx.x * 256 + threadIdx.x;
    if (idx < IND * HID) {             // W1t [128][512]
        int c = idx >> 9, k = idx & 511;
        W1t[idx] = (_Float16)W1[k * HID + c];
    }
    if (idx < HID * OUTD) {            // W2t [64][128]
        int c = idx >> 7, k = idx & 127;
        W2t[idx] = (_Float16)W2[k * OUTD + c];
    }
}

// ---------------- fused GEMM: H2 = relu(F @ W1) @ W2, f16 MFMA ----------------
__global__ __launch_bounds__(256) void fused_gemm_k(const float* __restrict__ F,
                                                    const _Float16* __restrict__ W1t,
                                                    const _Float16* __restrict__ W2t,
                                                    float* __restrict__ H2) {
    __shared__ _Float16 At[128 * 64];
    __shared__ _Float16 Bt[128 * 64];
    __shared__ _Float16 W2s[64 * 128];
    __shared__ _Float16 H1s[4][32 * 128];

    const int tid  = threadIdx.x;
    const int wid  = tid >> 6;
    const int lane = tid & 63;
    const int l15  = lane & 15;
    const int l4   = lane >> 4;
    const int brow = blockIdx.x * 128;

#pragma unroll
    for (int i = 0; i < 4; i++) {
        int idx = i * 256 + tid;
        int r = idx >> 4, s = idx & 15;
        int u = (r * 128 + s * 8) ^ ((r & 7) << 3);
        *(uint4*)(&W2s[u]) = *(const uint4*)(W2t + r * 128 + s * 8);
    }

    f32x4 acc[2][8];
#pragma unroll
    for (int mt = 0; mt < 2; mt++)
#pragma unroll
        for (int nt = 0; nt < 8; nt++) acc[mt][nt] = (f32x4)0.f;

    for (int chunk = 0; chunk < 8; chunk++) {
        const int kc = chunk * 64;
#pragma unroll
        for (int i = 0; i < 8; i++) {
            int idx = i * 256 + tid;
            int r = idx >> 4, c4 = idx & 15;
            int gr = brow + r; if (gr >= NN) gr = NN - 1;
            float4 v = *(const float4*)(F + (size_t)gr * IND + kc + c4 * 4);
            half4_t h; h.x = (_Float16)v.x; h.y = (_Float16)v.y; h.z = (_Float16)v.z; h.w = (_Float16)v.w;
            int u = (r * 64 + c4 * 4) ^ ((r & 7) << 3);
            *(half4_t*)(&At[u]) = h;
        }
#pragma unroll
        for (int i = 0; i < 4; i++) {
            int idx = i * 256 + tid;
            int r = idx >> 3, s = idx & 7;
            int u = (r * 64 + s * 8) ^ ((r & 7) << 3);
            *(uint4*)(&Bt[u]) = *(const uint4*)(W1t + (size_t)r * IND + kc + s * 8);
        }
        __syncthreads();
#pragma unroll
        for (int kk = 0; kk < 2; kk++) {
            const int kc2 = kk * 32;
            half8_t af[2];
#pragma unroll
            for (int mt = 0; mt < 2; mt++) {
                int rloc = wid * 32 + mt * 16 + l15;
                int u = (rloc * 64 + kc2 + l4 * 8) ^ ((rloc & 7) << 3);
                af[mt] = *(half8_t*)(&At[u]);
            }
#pragma unroll
            for (int nt = 0; nt < 8; nt++) {
                int cloc = nt * 16 + l15;
                int u = (cloc * 64 + kc2 + l4 * 8) ^ ((cloc & 7) << 3);
                half8_t bf = *(half8_t*)(&Bt[u]);
                acc[0][nt] = __builtin_amdgcn_mfma_f32_16x16x32_f16(af[0], bf, acc[0][nt], 0, 0, 0);
                acc[1][nt] = __builtin_amdgcn_mfma_f32_16x16x32_f16(af[1], bf, acc[1][nt], 0, 0, 0);
            }
        }
        __syncthreads();
    }

#pragma unroll
    for (int mt = 0; mt < 2; mt++)
#pragma unroll
        for (int nt = 0; nt < 8; nt++)
#pragma unroll
            for (int r = 0; r < 4; r++) {
                int rloc = mt * 16 + l4 * 4 + r;
                int col  = nt * 16 + l15;
                float v = acc[mt][nt][r];
                v = v > 0.f ? v : 0.f;
                int u = (rloc * 128 + col) ^ ((rloc & 7) << 3);
                H1s[wid][u] = (_Float16)v;
            }

    f32x4 acc2[2][4];
#pragma unroll
    for (int mt = 0; mt < 2; mt++)
#pragma unroll
        for (int nt = 0; nt < 4; nt++) acc2[mt][nt] = (f32x4)0.f;

#pragma unroll
    for (int kk = 0; kk < 4; kk++) {
        const int kc = kk * 32;
        half8_t a2[2];
#pragma unroll
        for (int mt = 0; mt < 2; mt++) {
            int rloc = mt * 16 + l15;
            int u = (rloc * 128 + kc + l4 * 8) ^ ((rloc & 7) << 3);
            a2[mt] = *(half8_t*)(&H1s[wid][u]);
        }
#pragma unroll
        for (int nt = 0; nt < 4; nt++) {
            int c = nt * 16 + l15;
            int u = (c * 128 + kc + l4 * 8) ^ ((c & 7) << 3);
            half8_t b2 = *(half8_t*)(&W2s[u]);
            acc2[0][nt] = __builtin_amdgcn_mfma_f32_16x16x32_f16(a2[0], b2, acc2[0][nt], 0, 0, 0);
            acc2[1][nt] = __builtin_amdgcn_mfma_f32_16x16x32_f16(a2[1], b2, acc2[1][nt], 0, 0, 0);
        }
    }
#pragma unroll
    for (int mt = 0; mt < 2; mt++)
#pragma unroll
        for (int nt = 0; nt < 4; nt++)
#pragma unroll
            for (int r = 0; r < 4; r++) {
                int grow = brow + wid * 32 + mt * 16 + l4 * 4 + r;
                if (grow < NN) H2[(size_t)grow * OUTD + nt * 16 + l15] = acc2[mt][nt][r];
            }
}

// ---------------- bucket partition (no global atomics) ----------------
// counts[b*NB + j] = #edges of block-chunk j landing in bucket b
__global__ __launch_bounds__(256) void count_k(const int* __restrict__ dst,
                                               int* __restrict__ counts, int nE, int CH) {
    __shared__ int bins[NBUCK];
    const int j = blockIdx.x, tid = threadIdx.x;
    for (int b = tid; b < NBUCK; b += 256) bins[b] = 0;
    __syncthreads();
    int lo = j * CH, hi = min(lo + CH, nE);
    for (int e = lo + tid; e < hi; e += 256) atomicAdd(&bins[dst[e] >> 7], 1);
    __syncthreads();
    for (int b = tid; b < NBUCK; b += 256) counts[b * NB + j] = bins[b];
}

// bsum[b] = total edges in bucket b
__global__ __launch_bounds__(128) void bsum_k(const int* __restrict__ counts,
                                              int* __restrict__ bsum) {
    __shared__ int s[128];
    const int b = blockIdx.x, t = threadIdx.x;
    s[t] = counts[b * NB + t];
    __syncthreads();
    for (int off = 64; off > 0; off >>= 1) {
        if (t < off) s[t] += s[t + off];
        __syncthreads();
    }
    if (t == 0) bsum[b] = s[0];
}

// exclusive scan of bsum -> bucketStart[0..NBUCK]
__global__ __launch_bounds__(1024) void scan_top_k(const int* __restrict__ bsum,
                                                   int* __restrict__ bucketStart, int n) {
    __shared__ int s[1024];
    const int t = threadIdx.x;
    int v = (t < n) ? bsum[t] : 0;
    s[t] = v;
    __syncthreads();
    for (int off = 1; off < 1024; off <<= 1) {
        int x = (t >= off) ? s[t - off] : 0;
        __syncthreads();
        s[t] += x;
        __syncthreads();
    }
    if (t < n) bucketStart[t] = s[t] - v;
    if (t == n - 1) bucketStart[n] = s[t];
}

// counts[b][j] -> global write offset = bucketStart[b] + sum_{j'<j} counts[b][j']
__global__ __launch_bounds__(128) void boff_k(int* __restrict__ counts,
                                              const int* __restrict__ bucketStart) {
    __shared__ int s[128];
    const int b = blockIdx.x, t = threadIdx.x;
    int v = counts[b * NB + t];
    s[t] = v;
    __syncthreads();
    for (int off = 1; off < 128; off <<= 1) {
        int x = (t >= off) ? s[t - off] : 0;
        __syncthreads();
        s[t] += x;
        __syncthreads();
    }
    counts[b * NB + t] = bucketStart[b] + s[t] - v;
}

// scatter edges into bucket-contiguous edata; cursors live in LDS
__global__ __launch_bounds__(256) void part_k(const int* __restrict__ src,
                                              const int* __restrict__ dst,
                                              const float* __restrict__ ew,
                                              const int* __restrict__ offsets,
                                              uint2* __restrict__ edata, int nE, int CH) {
    __shared__ int cur[NBUCK];
    const int j = blockIdx.x, tid = threadIdx.x;
    for (int b = tid; b < NBUCK; b += 256) cur[b] = offsets[b * NB + j];
    __syncthreads();
    int lo = j * CH, hi = min(lo + CH, nE);
    for (int e = lo + tid; e < hi; e += 256) {
        int d = dst[e];
        int b = d >> 7;
        int pos = atomicAdd(&cur[b], 1);
        edata[pos] = make_uint2(((unsigned)(d & 127) << 17) | (unsigned)src[e],
                                (unsigned)__float_as_int(ew[e]));
    }
}

// ---------------- propagate: block = bucket, LDS acc [128 dst][64 feat] ----------------
__global__ __launch_bounds__(256) void prop_k(const float* __restrict__ H,
                                              const uint2* __restrict__ edata,
                                              const int* __restrict__ bucketStart,
                                              float* __restrict__ Z) {
    __shared__ float acc[128 * 64];   // 32 KB
    const int b = blockIdx.x, tid = threadIdx.x;
    const int wid = tid >> 6, lane = tid & 63;

    float4* a4 = (float4*)acc;
    for (int i = tid; i < 2048; i += 256) a4[i] = make_float4(0.f, 0.f, 0.f, 0.f);
    __syncthreads();

    const int beg = bucketStart[b], end = bucketStart[b + 1];
    int i = beg + wid;
    for (; i + 4 < end; i += 8) {     // unroll 2 per wave (stride 4 waves)
        uint2 r0 = edata[i], r1 = edata[i + 4];
        float h0 = H[(size_t)(r0.x & 0x1FFFFu) * OUTD + lane];
        float h1 = H[(size_t)(r1.x & 0x1FFFFu) * OUTD + lane];
        atomicAdd(&acc[(r0.x >> 17) * OUTD + lane], __int_as_float((int)r0.y) * h0);
        atomicAdd(&acc[(r1.x >> 17) * OUTD + lane], __int_as_float((int)r1.y) * h1);
    }
    for (; i < end; i += 4) {
        uint2 r = edata[i];
        atomicAdd(&acc[(r.x >> 17) * OUTD + lane],
                  __int_as_float((int)r.y) * H[(size_t)(r.x & 0x1FFFFu) * OUTD + lane]);
    }
    __syncthreads();

    const int base = b * 128;
    for (int k = tid; k < 2048; k += 256) {
        int r = k >> 4;
        if (base + r < NN) ((float4*)(Z + (size_t)(base + r) * OUTD))[k & 15] = a4[k];
    }
}

extern "C" void kernel_launch(void* const* d_in, const int* in_sizes, int n_in,
                              void* d_out, int out_size, void* d_ws, size_t ws_size,
                              hipStream_t stream) {
    const float* F   = (const float*)d_in[0];
    const float* W1  = (const float*)d_in[1];
    const float* W2  = (const float*)d_in[2];
    const float* ew  = (const float*)d_in[3];
    const int*   src = (const int*)d_in[4];
    const int*   dst = (const int*)d_in[5];
    float* out = (float*)d_out;
    const int nE = in_sizes[3];

    // ---- workspace layout ----
    char* p = (char*)d_ws;
    float*     h2        = (float*)p;     p += (size_t)NN * OUTD * sizeof(float);      // 25.6 MB
    float*     z1        = (float*)p;     p += (size_t)NN * OUTD * sizeof(float);      // 25.6 MB
    _Float16*  W1t       = (_Float16*)p;  p += (size_t)HID * IND * sizeof(_Float16);
    _Float16*  W2t       = (_Float16*)p;  p += (size_t)OUTD * HID * sizeof(_Float16);
    int*       counts    = (int*)p;       p += (size_t)NBUCK * NB * sizeof(int);       // 400 KB
    int*       bsum      = (int*)p;       p += (size_t)NBUCK * sizeof(int);
    int*       bucketStart=(int*)p;       p += (size_t)(NBUCK + 16) * sizeof(int);
    uint2*     edata     = (uint2*)p;     p += (size_t)nE * sizeof(uint2);             // 25.6 MB

    const int CH = (nE + NB - 1) / NB;

    // ---- bucket partition (no global atomics) ----
    count_k<<<NB, 256, 0, stream>>>(dst, counts, nE, CH);
    bsum_k<<<NBUCK, 128, 0, stream>>>(counts, bsum);
    scan_top_k<<<1, 1024, 0, stream>>>(bsum, bucketStart, NBUCK);
    boff_k<<<NBUCK, 128, 0, stream>>>(counts, bucketStart);
    part_k<<<NB, 256, 0, stream>>>(src, dst, ew, counts, edata, nE, CH);

    // ---- fused NN layers (f16 MFMA) ----
    prep_k<<<(IND * HID + 255) / 256, 256, 0, stream>>>(W1, W2, W1t, W2t);
    fused_gemm_k<<<(NN + 127) / 128, 256, 0, stream>>>(F, W1t, W2t, h2);

    // ---- 2x bucketed propagate ----
    prop_k<<<NBUCK, 256, 0, stream>>>(h2, edata, bucketStart, z1);
    prop_k<<<NBUCK, 256, 0, stream>>>(z1, edata, bucketStart, out);
}

// Round 5
// 422.679 us; speedup vs baseline: 6.8123x; 6.8123x over previous
//
#include <hip/hip_runtime.h>

#define NN    100000
#define IND   512
#define HID   128
#define OUTD  64
#define NBUCK 782          // ceil(NN/128); bucket = dst >> 7
#define NB    128          // partition blocks

typedef _Float16 half8_t __attribute__((ext_vector_type(8)));
typedef _Float16 half4_t __attribute__((ext_vector_type(4)));
typedef float f32x4 __attribute__((ext_vector_type(4)));

// ---------------- prep: W1t[c][k] = (f16)W1[k][c], W2t[c][k] = (f16)W2[k][c] ----------------
__global__ __launch_bounds__(256) void prep_k(const float* __restrict__ W1,
                                              const float* __restrict__ W2,
                                              _Float16* __restrict__ W1t,
                                              _Float16* __restrict__ W2t) {
    int idx = blockIdx.x * 256 + threadIdx.x;
    if (idx < IND * HID) {             // W1t [128][512]
        int c = idx >> 9, k = idx & 511;
        W1t[idx] = (_Float16)W1[k * HID + c];
    }
    if (idx < HID * OUTD) {            // W2t [64][128]
        int c = idx >> 7, k = idx & 127;
        W2t[idx] = (_Float16)W2[k * OUTD + c];
    }
}

// ---------------- fused GEMM: H2 = relu(F @ W1) @ W2, f16 MFMA, f16 output ----------------
__global__ __launch_bounds__(256) void fused_gemm_k(const float* __restrict__ F,
                                                    const _Float16* __restrict__ W1t,
                                                    const _Float16* __restrict__ W2t,
                                                    _Float16* __restrict__ H2) {
    __shared__ _Float16 At[128 * 64];
    __shared__ _Float16 Bt[128 * 64];
    __shared__ _Float16 W2s[64 * 128];
    __shared__ _Float16 H1s[4][32 * 128];

    const int tid  = threadIdx.x;
    const int wid  = tid >> 6;
    const int lane = tid & 63;
    const int l15  = lane & 15;
    const int l4   = lane >> 4;
    const int brow = blockIdx.x * 128;

#pragma unroll
    for (int i = 0; i < 4; i++) {
        int idx = i * 256 + tid;
        int r = idx >> 4, s = idx & 15;
        int u = (r * 128 + s * 8) ^ ((r & 7) << 3);
        *(uint4*)(&W2s[u]) = *(const uint4*)(W2t + r * 128 + s * 8);
    }

    f32x4 acc[2][8];
#pragma unroll
    for (int mt = 0; mt < 2; mt++)
#pragma unroll
        for (int nt = 0; nt < 8; nt++) acc[mt][nt] = (f32x4)0.f;

    for (int chunk = 0; chunk < 8; chunk++) {
        const int kc = chunk * 64;
#pragma unroll
        for (int i = 0; i < 8; i++) {
            int idx = i * 256 + tid;
            int r = idx >> 4, c4 = idx & 15;
            int gr = brow + r; if (gr >= NN) gr = NN - 1;
            float4 v = *(const float4*)(F + (size_t)gr * IND + kc + c4 * 4);
            half4_t h; h.x = (_Float16)v.x; h.y = (_Float16)v.y; h.z = (_Float16)v.z; h.w = (_Float16)v.w;
            int u = (r * 64 + c4 * 4) ^ ((r & 7) << 3);
            *(half4_t*)(&At[u]) = h;
        }
#pragma unroll
        for (int i = 0; i < 4; i++) {
            int idx = i * 256 + tid;
            int r = idx >> 3, s = idx & 7;
            int u = (r * 64 + s * 8) ^ ((r & 7) << 3);
            *(uint4*)(&Bt[u]) = *(const uint4*)(W1t + (size_t)r * IND + kc + s * 8);
        }
        __syncthreads();
#pragma unroll
        for (int kk = 0; kk < 2; kk++) {
            const int kc2 = kk * 32;
            half8_t af[2];
#pragma unroll
            for (int mt = 0; mt < 2; mt++) {
                int rloc = wid * 32 + mt * 16 + l15;
                int u = (rloc * 64 + kc2 + l4 * 8) ^ ((rloc & 7) << 3);
                af[mt] = *(half8_t*)(&At[u]);
            }
#pragma unroll
            for (int nt = 0; nt < 8; nt++) {
                int cloc = nt * 16 + l15;
                int u = (cloc * 64 + kc2 + l4 * 8) ^ ((cloc & 7) << 3);
                half8_t bf = *(half8_t*)(&Bt[u]);
                acc[0][nt] = __builtin_amdgcn_mfma_f32_16x16x32_f16(af[0], bf, acc[0][nt], 0, 0, 0);
                acc[1][nt] = __builtin_amdgcn_mfma_f32_16x16x32_f16(af[1], bf, acc[1][nt], 0, 0, 0);
            }
        }
        __syncthreads();
    }

#pragma unroll
    for (int mt = 0; mt < 2; mt++)
#pragma unroll
        for (int nt = 0; nt < 8; nt++)
#pragma unroll
            for (int r = 0; r < 4; r++) {
                int rloc = mt * 16 + l4 * 4 + r;
                int col  = nt * 16 + l15;
                float v = acc[mt][nt][r];
                v = v > 0.f ? v : 0.f;
                int u = (rloc * 128 + col) ^ ((rloc & 7) << 3);
                H1s[wid][u] = (_Float16)v;
            }

    f32x4 acc2[2][4];
#pragma unroll
    for (int mt = 0; mt < 2; mt++)
#pragma unroll
        for (int nt = 0; nt < 4; nt++) acc2[mt][nt] = (f32x4)0.f;

#pragma unroll
    for (int kk = 0; kk < 4; kk++) {
        const int kc = kk * 32;
        half8_t a2[2];
#pragma unroll
        for (int mt = 0; mt < 2; mt++) {
            int rloc = mt * 16 + l15;
            int u = (rloc * 128 + kc + l4 * 8) ^ ((rloc & 7) << 3);
            a2[mt] = *(half8_t*)(&H1s[wid][u]);
        }
#pragma unroll
        for (int nt = 0; nt < 4; nt++) {
            int c = nt * 16 + l15;
            int u = (c * 128 + kc + l4 * 8) ^ ((c & 7) << 3);
            half8_t b2 = *(half8_t*)(&W2s[u]);
            acc2[0][nt] = __builtin_amdgcn_mfma_f32_16x16x32_f16(a2[0], b2, acc2[0][nt], 0, 0, 0);
            acc2[1][nt] = __builtin_amdgcn_mfma_f32_16x16x32_f16(a2[1], b2, acc2[1][nt], 0, 0, 0);
        }
    }
#pragma unroll
    for (int mt = 0; mt < 2; mt++)
#pragma unroll
        for (int nt = 0; nt < 4; nt++)
#pragma unroll
            for (int r = 0; r < 4; r++) {
                int grow = brow + wid * 32 + mt * 16 + l4 * 4 + r;
                if (grow < NN) H2[(size_t)grow * OUTD + nt * 16 + l15] = (_Float16)acc2[mt][nt][r];
            }
}

// ---------------- bucket partition (no global atomics) ----------------
__global__ __launch_bounds__(256) void count_k(const int* __restrict__ dst,
                                               int* __restrict__ counts, int nE, int CH) {
    __shared__ int bins[NBUCK];
    const int j = blockIdx.x, tid = threadIdx.x;
    for (int b = tid; b < NBUCK; b += 256) bins[b] = 0;
    __syncthreads();
    int lo = j * CH, hi = min(lo + CH, nE);
    for (int e = lo + tid; e < hi; e += 256) atomicAdd(&bins[dst[e] >> 7], 1);
    __syncthreads();
    for (int b = tid; b < NBUCK; b += 256) counts[b * NB + j] = bins[b];
}

__global__ __launch_bounds__(128) void bsum_k(const int* __restrict__ counts,
                                              int* __restrict__ bsum) {
    __shared__ int s[128];
    const int b = blockIdx.x, t = threadIdx.x;
    s[t] = counts[b * NB + t];
    __syncthreads();
    for (int off = 64; off > 0; off >>= 1) {
        if (t < off) s[t] += s[t + off];
        __syncthreads();
    }
    if (t == 0) bsum[b] = s[0];
}

__global__ __launch_bounds__(1024) void scan_top_k(const int* __restrict__ bsum,
                                                   int* __restrict__ bucketStart, int n) {
    __shared__ int s[1024];
    const int t = threadIdx.x;
    int v = (t < n) ? bsum[t] : 0;
    s[t] = v;
    __syncthreads();
    for (int off = 1; off < 1024; off <<= 1) {
        int x = (t >= off) ? s[t - off] : 0;
        __syncthreads();
        s[t] += x;
        __syncthreads();
    }
    if (t < n) bucketStart[t] = s[t] - v;
    if (t == n - 1) bucketStart[n] = s[t];
}

__global__ __launch_bounds__(128) void boff_k(int* __restrict__ counts,
                                              const int* __restrict__ bucketStart) {
    __shared__ int s[128];
    const int b = blockIdx.x, t = threadIdx.x;
    int v = counts[b * NB + t];
    s[t] = v;
    __syncthreads();
    for (int off = 1; off < 128; off <<= 1) {
        int x = (t >= off) ? s[t - off] : 0;
        __syncthreads();
        s[t] += x;
        __syncthreads();
    }
    counts[b * NB + t] = bucketStart[b] + s[t] - v;
}

// scatter edges into bucket-contiguous edata; cursors in LDS
// payload: x = local_dst(7b)<<17 | src(17b), y = f32 weight bits
__global__ __launch_bounds__(256) void part_k(const int* __restrict__ src,
                                              const int* __restrict__ dst,
                                              const float* __restrict__ ew,
                                              const int* __restrict__ offsets,
                                              uint2* __restrict__ edata, int nE, int CH) {
    __shared__ int cur[NBUCK];
    const int j = blockIdx.x, tid = threadIdx.x;
    for (int b = tid; b < NBUCK; b += 256) cur[b] = offsets[b * NB + j];
    __syncthreads();
    int lo = j * CH, hi = min(lo + CH, nE);
    for (int e = lo + tid; e < hi; e += 256) {
        int d = dst[e];
        int b = d >> 7;
        int pos = atomicAdd(&cur[b], 1);
        edata[pos] = make_uint2(((unsigned)(d & 127) << 17) | (unsigned)src[e],
                                (unsigned)__float_as_int(ew[e]));
    }
}

// per-bucket counting sort -> exact dst-sorted packed edges + rowStart
// epack: src(17b)<<15 | q15 weight
__global__ __launch_bounds__(256) void sort_k(const uint2* __restrict__ edata,
                                              const int* __restrict__ bucketStart,
                                              unsigned* __restrict__ epack,
                                              int* __restrict__ rowStart) {
    __shared__ int bins[128];
    __shared__ int s[128];
    __shared__ int cur[128];
    const int b = blockIdx.x, tid = threadIdx.x;
    if (tid < 128) bins[tid] = 0;
    __syncthreads();
    const int beg = bucketStart[b], end = bucketStart[b + 1];
    for (int e = beg + tid; e < end; e += 256)
        atomicAdd(&bins[edata[e].x >> 17], 1);
    __syncthreads();
    if (tid < 128) s[tid] = bins[tid];
    __syncthreads();
    for (int off = 1; off < 128; off <<= 1) {
        int x = 0;
        if (tid < 128 && tid >= off) x = s[tid - off];
        __syncthreads();
        if (tid < 128) s[tid] += x;
        __syncthreads();
    }
    if (tid < 128) {
        int excl = beg + s[tid] - bins[tid];
        cur[tid] = excl;
        rowStart[b * 128 + tid] = excl;   // rowStart[NN] lands correctly (trailing bins are 0)
    }
    __syncthreads();
    for (int e = beg + tid; e < end; e += 256) {
        uint2 r = edata[e];
        int ld = r.x >> 17;
        int pos = atomicAdd(&cur[ld], 1);
        float w = __int_as_float((int)r.y);
        int q = (int)(w * 32768.f + 0.5f);
        if (q > 32767) q = 32767;
        epack[pos] = ((r.x & 0x1FFFFu) << 15) | (unsigned)q;
    }
}

// ---------------- pull propagate: wave per dst, lane = feature, f16 gather ----------------
template <bool LAST>
__global__ __launch_bounds__(256) void pull_k(const _Float16* __restrict__ H,
                                              const unsigned* __restrict__ ep,
                                              const int* __restrict__ rowStart,
                                              _Float16* __restrict__ Zh,
                                              float* __restrict__ Zf) {
    int wave = (int)((blockIdx.x * (long)blockDim.x + threadIdx.x) >> 6);
    int lane = threadIdx.x & 63;
    if (wave >= NN) return;
    int beg = rowStart[wave];
    int end = rowStart[wave + 1];
    float acc = 0.f;
    int i = beg;
    for (; i + 4 <= end; i += 4) {
        unsigned u0 = ep[i], u1 = ep[i + 1], u2 = ep[i + 2], u3 = ep[i + 3];
        float h0 = (float)H[(size_t)(u0 >> 15) * OUTD + lane];
        float h1 = (float)H[(size_t)(u1 >> 15) * OUTD + lane];
        float h2 = (float)H[(size_t)(u2 >> 15) * OUTD + lane];
        float h3 = (float)H[(size_t)(u3 >> 15) * OUTD + lane];
        acc += (float)(int)(u0 & 32767u) * h0;
        acc += (float)(int)(u1 & 32767u) * h1;
        acc += (float)(int)(u2 & 32767u) * h2;
        acc += (float)(int)(u3 & 32767u) * h3;
    }
    for (; i < end; i++) {
        unsigned u = ep[i];
        acc += (float)(int)(u & 32767u) * (float)H[(size_t)(u >> 15) * OUTD + lane];
    }
    acc *= (1.f / 32768.f);
    if (LAST) Zf[(size_t)wave * OUTD + lane] = acc;
    else      Zh[(size_t)wave * OUTD + lane] = (_Float16)acc;
}

extern "C" void kernel_launch(void* const* d_in, const int* in_sizes, int n_in,
                              void* d_out, int out_size, void* d_ws, size_t ws_size,
                              hipStream_t stream) {
    const float* F   = (const float*)d_in[0];
    const float* W1  = (const float*)d_in[1];
    const float* W2  = (const float*)d_in[2];
    const float* ew  = (const float*)d_in[3];
    const int*   src = (const int*)d_in[4];
    const int*   dst = (const int*)d_in[5];
    float* out = (float*)d_out;
    const int nE = in_sizes[3];

    // ---- workspace layout ----
    char* p = (char*)d_ws;
    _Float16*  h2        = (_Float16*)p;  p += (size_t)NN * OUTD * sizeof(_Float16);   // 12.8 MB
    _Float16*  z1        = (_Float16*)p;  p += (size_t)NN * OUTD * sizeof(_Float16);   // 12.8 MB
    _Float16*  W1t       = (_Float16*)p;  p += (size_t)HID * IND * sizeof(_Float16);
    _Float16*  W2t       = (_Float16*)p;  p += (size_t)OUTD * HID * sizeof(_Float16);
    int*       counts    = (int*)p;       p += (size_t)NBUCK * NB * sizeof(int);       // 400 KB
    int*       bsum      = (int*)p;       p += (size_t)NBUCK * sizeof(int);
    int*       bucketStart=(int*)p;       p += (size_t)(NBUCK + 16) * sizeof(int);
    int*       rowStart  = (int*)p;       p += (size_t)(NN + 160) * sizeof(int);       // 400 KB
    uint2*     edata     = (uint2*)p;     p += (size_t)nE * sizeof(uint2);             // 25.6 MB
    unsigned*  epack     = (unsigned*)p;  p += (size_t)nE * sizeof(unsigned);          // 12.8 MB

    const int CH = (nE + NB - 1) / NB;

    // ---- bucket partition + exact sort (no global atomics) ----
    count_k<<<NB, 256, 0, stream>>>(dst, counts, nE, CH);
    bsum_k<<<NBUCK, 128, 0, stream>>>(counts, bsum);
    scan_top_k<<<1, 1024, 0, stream>>>(bsum, bucketStart, NBUCK);
    boff_k<<<NBUCK, 128, 0, stream>>>(counts, bucketStart);
    part_k<<<NB, 256, 0, stream>>>(src, dst, ew, counts, edata, nE, CH);
    sort_k<<<NBUCK, 256, 0, stream>>>(edata, bucketStart, epack, rowStart);

    // ---- fused NN layers (f16 MFMA) ----
    prep_k<<<(IND * HID + 255) / 256, 256, 0, stream>>>(W1, W2, W1t, W2t);
    fused_gemm_k<<<(NN + 127) / 128, 256, 0, stream>>>(F, W1t, W2t, h2);

    // ---- 2x pull-propagate (f16 gathers, f32 accum) ----
    int blocks = (int)(((long)NN * 64 + 255) / 256);
    pull_k<false><<<blocks, 256, 0, stream>>>(h2, epack, rowStart, z1, nullptr);
    pull_k<true><<<blocks, 256, 0, stream>>>(z1, epack, rowStart, nullptr, out);
}

// Round 6
// 347.250 us; speedup vs baseline: 8.2921x; 1.2172x over previous
//
#include <hip/hip_runtime.h>

#define NN    100000
#define IND   512
#define HID   128
#define OUTD  64
#define NBUCK 782          // ceil(NN/128); bucket = dst >> 7
#define NB    256          // partition chunks

typedef _Float16 half8_t __attribute__((ext_vector_type(8)));
typedef _Float16 half4_t __attribute__((ext_vector_type(4)));
typedef float f32x4 __attribute__((ext_vector_type(4)));

// ---------------- prep: W1t[c][k] = (f16)W1[k][c], W2t[c][k] = (f16)W2[k][c] ----------------
__global__ __launch_bounds__(256) void prep_k(const float* __restrict__ W1,
                                              const float* __restrict__ W2,
                                              _Float16* __restrict__ W1t,
                                              _Float16* __restrict__ W2t) {
    int idx = blockIdx.x * 256 + threadIdx.x;
    if (idx < IND * HID) {             // W1t [128][512]
        int c = idx >> 9, k = idx & 511;
        W1t[idx] = (_Float16)W1[k * HID + c];
    }
    if (idx < HID * OUTD) {            // W2t [64][128]
        int c = idx >> 7, k = idx & 127;
        W2t[idx] = (_Float16)W2[k * OUTD + c];
    }
}

// ---------------- fused GEMM: H2 = relu(F @ W1) @ W2, f16 MFMA, f16 output ----------------
__global__ __launch_bounds__(256) void fused_gemm_k(const float* __restrict__ F,
                                                    const _Float16* __restrict__ W1t,
                                                    const _Float16* __restrict__ W2t,
                                                    _Float16* __restrict__ H2) {
    __shared__ _Float16 At[128 * 64];
    __shared__ _Float16 Bt[128 * 64];
    __shared__ _Float16 W2s[64 * 128];
    __shared__ _Float16 H1s[4][32 * 128];

    const int tid  = threadIdx.x;
    const int wid  = tid >> 6;
    const int lane = tid & 63;
    const int l15  = lane & 15;
    const int l4   = lane >> 4;
    const int brow = blockIdx.x * 128;

#pragma unroll
    for (int i = 0; i < 4; i++) {
        int idx = i * 256 + tid;
        int r = idx >> 4, s = idx & 15;
        int u = (r * 128 + s * 8) ^ ((r & 7) << 3);
        *(uint4*)(&W2s[u]) = *(const uint4*)(W2t + r * 128 + s * 8);
    }

    f32x4 acc[2][8];
#pragma unroll
    for (int mt = 0; mt < 2; mt++)
#pragma unroll
        for (int nt = 0; nt < 8; nt++) acc[mt][nt] = (f32x4)0.f;

    for (int chunk = 0; chunk < 8; chunk++) {
        const int kc = chunk * 64;
#pragma unroll
        for (int i = 0; i < 8; i++) {
            int idx = i * 256 + tid;
            int r = idx >> 4, c4 = idx & 15;
            int gr = brow + r; if (gr >= NN) gr = NN - 1;
            float4 v = *(const float4*)(F + (size_t)gr * IND + kc + c4 * 4);
            half4_t h; h.x = (_Float16)v.x; h.y = (_Float16)v.y; h.z = (_Float16)v.z; h.w = (_Float16)v.w;
            int u = (r * 64 + c4 * 4) ^ ((r & 7) << 3);
            *(half4_t*)(&At[u]) = h;
        }
#pragma unroll
        for (int i = 0; i < 4; i++) {
            int idx = i * 256 + tid;
            int r = idx >> 3, s = idx & 7;
            int u = (r * 64 + s * 8) ^ ((r & 7) << 3);
            *(uint4*)(&Bt[u]) = *(const uint4*)(W1t + (size_t)r * IND + kc + s * 8);
        }
        __syncthreads();
#pragma unroll
        for (int kk = 0; kk < 2; kk++) {
            const int kc2 = kk * 32;
            half8_t af[2];
#pragma unroll
            for (int mt = 0; mt < 2; mt++) {
                int rloc = wid * 32 + mt * 16 + l15;
                int u = (rloc * 64 + kc2 + l4 * 8) ^ ((rloc & 7) << 3);
                af[mt] = *(half8_t*)(&At[u]);
            }
#pragma unroll
            for (int nt = 0; nt < 8; nt++) {
                int cloc = nt * 16 + l15;
                int u = (cloc * 64 + kc2 + l4 * 8) ^ ((cloc & 7) << 3);
                half8_t bf = *(half8_t*)(&Bt[u]);
                acc[0][nt] = __builtin_amdgcn_mfma_f32_16x16x32_f16(af[0], bf, acc[0][nt], 0, 0, 0);
                acc[1][nt] = __builtin_amdgcn_mfma_f32_16x16x32_f16(af[1], bf, acc[1][nt], 0, 0, 0);
            }
        }
        __syncthreads();
    }

#pragma unroll
    for (int mt = 0; mt < 2; mt++)
#pragma unroll
        for (int nt = 0; nt < 8; nt++)
#pragma unroll
            for (int r = 0; r < 4; r++) {
                int rloc = mt * 16 + l4 * 4 + r;
                int col  = nt * 16 + l15;
                float v = acc[mt][nt][r];
                v = v > 0.f ? v : 0.f;
                int u = (rloc * 128 + col) ^ ((rloc & 7) << 3);
                H1s[wid][u] = (_Float16)v;
            }

    f32x4 acc2[2][4];
#pragma unroll
    for (int mt = 0; mt < 2; mt++)
#pragma unroll
        for (int nt = 0; nt < 4; nt++) acc2[mt][nt] = (f32x4)0.f;

#pragma unroll
    for (int kk = 0; kk < 4; kk++) {
        const int kc = kk * 32;
        half8_t a2[2];
#pragma unroll
        for (int mt = 0; mt < 2; mt++) {
            int rloc = mt * 16 + l15;
            int u = (rloc * 128 + kc + l4 * 8) ^ ((rloc & 7) << 3);
            a2[mt] = *(half8_t*)(&H1s[wid][u]);
        }
#pragma unroll
        for (int nt = 0; nt < 4; nt++) {
            int c = nt * 16 + l15;
            int u = (c * 128 + kc + l4 * 8) ^ ((c & 7) << 3);
            half8_t b2 = *(half8_t*)(&W2s[u]);
            acc2[0][nt] = __builtin_amdgcn_mfma_f32_16x16x32_f16(a2[0], b2, acc2[0][nt], 0, 0, 0);
            acc2[1][nt] = __builtin_amdgcn_mfma_f32_16x16x32_f16(a2[1], b2, acc2[1][nt], 0, 0, 0);
        }
    }
#pragma unroll
    for (int mt = 0; mt < 2; mt++)
#pragma unroll
        for (int nt = 0; nt < 4; nt++)
#pragma unroll
            for (int r = 0; r < 4; r++) {
                int grow = brow + wid * 32 + mt * 16 + l4 * 4 + r;
                if (grow < NN) H2[(size_t)grow * OUTD + nt * 16 + l15] = (_Float16)acc2[mt][nt][r];
            }
}

// ---------------- bucket partition (no global atomics; wide launch) ----------------
__global__ __launch_bounds__(1024) void count_k(const int* __restrict__ dst,
                                                int* __restrict__ counts, int nE, int CH) {
    __shared__ int bins[NBUCK];
    const int j = blockIdx.x, tid = threadIdx.x;
    for (int b = tid; b < NBUCK; b += 1024) bins[b] = 0;
    __syncthreads();
    int lo = j * CH, hi = min(lo + CH, nE);
    for (int e = lo + tid; e < hi; e += 1024) atomicAdd(&bins[dst[e] >> 7], 1);
    __syncthreads();
    for (int b = tid; b < NBUCK; b += 1024) counts[b * NB + j] = bins[b];
}

__global__ __launch_bounds__(256) void bsum_k(const int* __restrict__ counts,
                                              int* __restrict__ bsum) {
    __shared__ int s[256];
    const int b = blockIdx.x, t = threadIdx.x;
    s[t] = counts[b * NB + t];
    __syncthreads();
    for (int off = 128; off > 0; off >>= 1) {
        if (t < off) s[t] += s[t + off];
        __syncthreads();
    }
    if (t == 0) bsum[b] = s[0];
}

__global__ __launch_bounds__(1024) void scan_top_k(const int* __restrict__ bsum,
                                                   int* __restrict__ bucketStart, int n) {
    __shared__ int s[1024];
    const int t = threadIdx.x;
    int v = (t < n) ? bsum[t] : 0;
    s[t] = v;
    __syncthreads();
    for (int off = 1; off < 1024; off <<= 1) {
        int x = (t >= off) ? s[t - off] : 0;
        __syncthreads();
        s[t] += x;
        __syncthreads();
    }
    if (t < n) bucketStart[t] = s[t] - v;
    if (t == n - 1) bucketStart[n] = s[t];
}

__global__ __launch_bounds__(256) void boff_k(int* __restrict__ counts,
                                              const int* __restrict__ bucketStart) {
    __shared__ int s[256];
    const int b = blockIdx.x, t = threadIdx.x;
    int v = counts[b * NB + t];
    s[t] = v;
    __syncthreads();
    for (int off = 1; off < 256; off <<= 1) {
        int x = (t >= off) ? s[t - off] : 0;
        __syncthreads();
        s[t] += x;
        __syncthreads();
    }
    counts[b * NB + t] = bucketStart[b] + s[t] - v;
}

// scatter edges into bucket-contiguous edata; cursors in LDS
// payload: x = local_dst(7b)<<17 | src(17b), y = f32 weight bits
__global__ __launch_bounds__(1024) void part_k(const int* __restrict__ src,
                                               const int* __restrict__ dst,
                                               const float* __restrict__ ew,
                                               const int* __restrict__ offsets,
                                               uint2* __restrict__ edata, int nE, int CH) {
    __shared__ int cur[NBUCK];
    const int j = blockIdx.x, tid = threadIdx.x;
    for (int b = tid; b < NBUCK; b += 1024) cur[b] = offsets[b * NB + j];
    __syncthreads();
    int lo = j * CH, hi = min(lo + CH, nE);
    for (int e = lo + tid; e < hi; e += 1024) {
        int d = dst[e];
        int b = d >> 7;
        int pos = atomicAdd(&cur[b], 1);
        edata[pos] = make_uint2(((unsigned)(d & 127) << 17) | (unsigned)src[e],
                                (unsigned)__float_as_int(ew[e]));
    }
}

// per-bucket counting sort -> exact dst-sorted packed edges + rowStart
// epack: src(17b)<<15 | q15 weight
__global__ __launch_bounds__(256) void sort_k(const uint2* __restrict__ edata,
                                              const int* __restrict__ bucketStart,
                                              unsigned* __restrict__ epack,
                                              int* __restrict__ rowStart) {
    __shared__ int bins[128];
    __shared__ int s[128];
    __shared__ int cur[128];
    const int b = blockIdx.x, tid = threadIdx.x;
    if (tid < 128) bins[tid] = 0;
    __syncthreads();
    const int beg = bucketStart[b], end = bucketStart[b + 1];
    for (int e = beg + tid; e < end; e += 256)
        atomicAdd(&bins[edata[e].x >> 17], 1);
    __syncthreads();
    if (tid < 128) s[tid] = bins[tid];
    __syncthreads();
    for (int off = 1; off < 128; off <<= 1) {
        int x = 0;
        if (tid < 128 && tid >= off) x = s[tid - off];
        __syncthreads();
        if (tid < 128) s[tid] += x;
        __syncthreads();
    }
    if (tid < 128) {
        int excl = beg + s[tid] - bins[tid];
        cur[tid] = excl;
        rowStart[b * 128 + tid] = excl;   // rowStart[NN] lands correctly (trailing bins are 0)
    }
    __syncthreads();
    for (int e = beg + tid; e < end; e += 256) {
        uint2 r = edata[e];
        int ld = r.x >> 17;
        int pos = atomicAdd(&cur[ld], 1);
        float w = __int_as_float((int)r.y);
        int q = (int)(w * 32768.f + 0.5f);
        if (q > 32767) q = 32767;
        epack[pos] = ((r.x & 0x1FFFFu) << 15) | (unsigned)q;
    }
}

// ---------------- pull propagate: wave per dst, lane = feature, f16 gather ----------------
template <bool LAST>
__global__ __launch_bounds__(256) void pull_k(const _Float16* __restrict__ H,
                                              const unsigned* __restrict__ ep,
                                              const int* __restrict__ rowStart,
                                              _Float16* __restrict__ Zh,
                                              float* __restrict__ Zf) {
    int wave = (int)((blockIdx.x * (long)blockDim.x + threadIdx.x) >> 6);
    int lane = threadIdx.x & 63;
    if (wave >= NN) return;
    int beg = rowStart[wave];
    int end = rowStart[wave + 1];
    float acc = 0.f;
    int i = beg;
    for (; i + 4 <= end; i += 4) {
        unsigned u0 = ep[i], u1 = ep[i + 1], u2 = ep[i + 2], u3 = ep[i + 3];
        float h0 = (float)H[(size_t)(u0 >> 15) * OUTD + lane];
        float h1 = (float)H[(size_t)(u1 >> 15) * OUTD + lane];
        float h2 = (float)H[(size_t)(u2 >> 15) * OUTD + lane];
        float h3 = (float)H[(size_t)(u3 >> 15) * OUTD + lane];
        acc += (float)(int)(u0 & 32767u) * h0;
        acc += (float)(int)(u1 & 32767u) * h1;
        acc += (float)(int)(u2 & 32767u) * h2;
        acc += (float)(int)(u3 & 32767u) * h3;
    }
    for (; i < end; i++) {
        unsigned u = ep[i];
        acc += (float)(int)(u & 32767u) * (float)H[(size_t)(u >> 15) * OUTD + lane];
    }
    acc *= (1.f / 32768.f);
    if (LAST) Zf[(size_t)wave * OUTD + lane] = acc;
    else      Zh[(size_t)wave * OUTD + lane] = (_Float16)acc;
}

extern "C" void kernel_launch(void* const* d_in, const int* in_sizes, int n_in,
                              void* d_out, int out_size, void* d_ws, size_t ws_size,
                              hipStream_t stream) {
    const float* F   = (const float*)d_in[0];
    const float* W1  = (const float*)d_in[1];
    const float* W2  = (const float*)d_in[2];
    const float* ew  = (const float*)d_in[3];
    const int*   src = (const int*)d_in[4];
    const int*   dst = (const int*)d_in[5];
    float* out = (float*)d_out;
    const int nE = in_sizes[3];

    // ---- workspace layout ----
    char* p = (char*)d_ws;
    _Float16*  h2        = (_Float16*)p;  p += (size_t)NN * OUTD * sizeof(_Float16);   // 12.8 MB
    _Float16*  z1        = (_Float16*)p;  p += (size_t)NN * OUTD * sizeof(_Float16);   // 12.8 MB
    _Float16*  W1t       = (_Float16*)p;  p += (size_t)HID * IND * sizeof(_Float16);
    _Float16*  W2t       = (_Float16*)p;  p += (size_t)OUTD * HID * sizeof(_Float16);
    int*       counts    = (int*)p;       p += (size_t)NBUCK * NB * sizeof(int);       // 800 KB
    int*       bsum      = (int*)p;       p += (size_t)NBUCK * sizeof(int);
    int*       bucketStart=(int*)p;       p += (size_t)(NBUCK + 16) * sizeof(int);
    int*       rowStart  = (int*)p;       p += (size_t)(NN + 160) * sizeof(int);       // 400 KB
    uint2*     edata     = (uint2*)p;     p += (size_t)nE * sizeof(uint2);             // 25.6 MB
    unsigned*  epack     = (unsigned*)p;  p += (size_t)nE * sizeof(unsigned);          // 12.8 MB

    const int CH = (nE + NB - 1) / NB;   // 12500

    // ---- bucket partition + exact sort (no global atomics) ----
    count_k<<<NB, 1024, 0, stream>>>(dst, counts, nE, CH);
    bsum_k<<<NBUCK, 256, 0, stream>>>(counts, bsum);
    scan_top_k<<<1, 1024, 0, stream>>>(bsum, bucketStart, NBUCK);
    boff_k<<<NBUCK, 256, 0, stream>>>(counts, bucketStart);
    part_k<<<NB, 1024, 0, stream>>>(src, dst, ew, counts, edata, nE, CH);
    sort_k<<<NBUCK, 256, 0, stream>>>(edata, bucketStart, epack, rowStart);

    // ---- fused NN layers (f16 MFMA) ----
    prep_k<<<(IND * HID + 255) / 256, 256, 0, stream>>>(W1, W2, W1t, W2t);
    fused_gemm_k<<<(NN + 127) / 128, 256, 0, stream>>>(F, W1t, W2t, h2);

    // ---- 2x pull-propagate (f16 gathers, f32 accum) ----
    int blocks = (int)(((long)NN * 64 + 255) / 256);
    pull_k<false><<<blocks, 256, 0, stream>>>(h2, epack, rowStart, z1, nullptr);
    pull_k<true><<<blocks, 256, 0, stream>>>(z1, epack, rowStart, nullptr, out);
}